// Round 2
// baseline (744.167 us; speedup 1.0000x reference)
//
#include <hip/hip_runtime.h>
#include <math.h>
#include <cstddef>

#define B_ 16
#define T_ 256
#define D_ 128
#define H_ 128
#define L_ 4
#define G_ 512          // 4*H
#define NC_ 10
#define EPS_ 1e-5f
#define C_ 16           // pipeline chunk (timesteps per flag)
#define NCHUNK_ (T_ / C_)

// padded LDS row: +4 floats per 32 -> 144-float rows; quarter q at q*36 floats
#define HROW_ 144
#define HOFF(k) ((k) + (((k) >> 5) << 2))

typedef float f4v __attribute__((ext_vector_type(4)));

// 8 x global_load_dwordx4 -> 32 floats resident (compiler cannot remat asm)
#define LOAD_W8(w, base)                                                   \
    asm volatile(                                                          \
        "global_load_dwordx4 %0, %8, off\n\t"                             \
        "global_load_dwordx4 %1, %8, off offset:16\n\t"                   \
        "global_load_dwordx4 %2, %8, off offset:32\n\t"                   \
        "global_load_dwordx4 %3, %8, off offset:48\n\t"                   \
        "global_load_dwordx4 %4, %8, off offset:64\n\t"                   \
        "global_load_dwordx4 %5, %8, off offset:80\n\t"                   \
        "global_load_dwordx4 %6, %8, off offset:96\n\t"                   \
        "global_load_dwordx4 %7, %8, off offset:112\n\t"                  \
        "s_waitcnt vmcnt(0)"                                               \
        : "=&v"(w[0]), "=&v"(w[1]), "=&v"(w[2]), "=&v"(w[3]),              \
          "=&v"(w[4]), "=&v"(w[5]), "=&v"(w[6]), "=&v"(w[7])               \
        : "v"(base)                                                        \
        : "memory")

// 32-k partial dot against pre-loaded h registers (params avoid x/y/z/w tokens)
#define DOT32R(dst_, warr_, hvarr_)                                        \
    {                                                                      \
        float d0_ = 0.f, d1_ = 0.f;                                        \
        _Pragma("unroll")                                                  \
        for (int j_ = 0; j_ < 8; j_++) {                                   \
            d0_ = fmaf(warr_[j_].x, hvarr_[j_].x, d0_);                    \
            d1_ = fmaf(warr_[j_].y, hvarr_[j_].y, d1_);                    \
            d0_ = fmaf(warr_[j_].z, hvarr_[j_].z, d0_);                    \
            d1_ = fmaf(warr_[j_].w, hvarr_[j_].w, d1_);                    \
        }                                                                  \
        dst_ = d0_ + d1_;                                                  \
    }

// ---------------- device helpers ----------------
__device__ __forceinline__ float sigmoid_(float x) {
    x = fminf(fmaxf(x, -30.f), 30.f);
    return 1.f / (1.f + __expf(-x));
}
__device__ __forceinline__ float tanh_(float x) {
    float ax = fminf(fabsf(x), 15.f);
    float e = __expf(2.f * ax);
    float t = 1.f - 2.f / (e + 1.f);
    return copysignf(t, x);
}
__device__ __forceinline__ void wait_ge_(int* p, int v) {
    if (__hip_atomic_load(p, __ATOMIC_RELAXED, __HIP_MEMORY_SCOPE_AGENT) < v) {
        do { __builtin_amdgcn_s_sleep(1); }
        while (__hip_atomic_load(p, __ATOMIC_RELAXED, __HIP_MEMORY_SCOPE_AGENT) < v);
    }
    (void)__hip_atomic_load(p, __ATOMIC_ACQUIRE, __HIP_MEMORY_SCOPE_AGENT);
}
__device__ __forceinline__ void ast_(float* p, float v) {
    __hip_atomic_store(p, v, __ATOMIC_RELAXED, __HIP_MEMORY_SCOPE_AGENT);
}
__device__ __forceinline__ float ald_(const float* p) {
    return __hip_atomic_load(p, __ATOMIC_RELAXED, __HIP_MEMORY_SCOPE_AGENT);
}

// load 2 steps x 4 gates of ring values for this lane's row r
#define RING_LD8(dst_, gp_)                                                \
    {                                                                      \
        dst_[0] = ald_((gp_) + r);            dst_[1] = ald_((gp_) + 128 + r); \
        dst_[2] = ald_((gp_) + 256 + r);      dst_[3] = ald_((gp_) + 384 + r); \
        dst_[4] = ald_((gp_) + G_ + r);       dst_[5] = ald_((gp_) + G_ + 128 + r); \
        dst_[6] = ald_((gp_) + G_ + 256 + r); dst_[7] = ald_((gp_) + G_ + 384 + r); \
    }

// one LSTM timestep for stream SB (0/1): read h from LDS row SB*2+RD,
// write h to LDS row SB*2+WR, per-step global h store from q==0 lanes.
// NO barrier inside: caller places one barrier per (A,B) step pair.
#define REC_STEP2(SB, RD, WR, PI, PF, PG, PO, CC, HST)                     \
    {                                                                      \
        const f4v* hb4_ = (const f4v*)(shbuf + ((SB) * 2 + (RD)) * HROW_ + q * 36); \
        f4v hv[8];                                                         \
        _Pragma("unroll")                                                  \
        for (int jj_ = 0; jj_ < 8; jj_++) hv[jj_] = hb4_[jj_];             \
        float zi, zf, zg, zo;                                              \
        DOT32R(zi, w0, hv);                                                \
        DOT32R(zf, w1, hv);                                                \
        DOT32R(zg, w2, hv);                                                \
        DOT32R(zo, w3, hv);                                                \
        zi += __shfl_xor(zi, 1); zi += __shfl_xor(zi, 2);                  \
        zf += __shfl_xor(zf, 1); zf += __shfl_xor(zf, 2);                  \
        zg += __shfl_xor(zg, 1); zg += __shfl_xor(zg, 2);                  \
        zo += __shfl_xor(zo, 1); zo += __shfl_xor(zo, 2);                  \
        zi += (PI); zf += (PF); zg += (PG); zo += (PO);                    \
        float ai = sigmoid_(zi), af = sigmoid_(zf);                        \
        float ag = tanh_(zg),    ao = sigmoid_(zo);                        \
        CC = fmaf(af, CC, ai * ag);                                        \
        float hn = ao * tanh_(CC);                                         \
        if (q == 0) {                                                      \
            shbuf[((SB) * 2 + (WR)) * HROW_ + HOFF(r)] = hn;               \
            ast_((HST), hn);                                               \
        }                                                                  \
        (HST) += 128;                                                      \
    }

// ---------------- megascan: EVERYTHING (stats + scan + riders + score/tail) -------
// 208 WGs x 512 thr (waves_per_eu(2,2) => 1 WG/CU cap => all co-resident):
//   wg[0..31]    rec(l, batch-pair): 2 batches share weight regs; one barrier
//                serves both streams' steps (halves per-step barrier cost)
//   wg[32..95]   xproj(l=0..3,b): l==0 waits flag_norm[b] for factors
//   wg[96..111]  px rider (waits flag_norm[b]) -> flag_px[b]
//   wg[112..127] h3-stats rider -> flag_ln[b]
//   wg[128..191] score/tail rider (4/batch): ph GEMM + scores; cnt sync;
//                softmax + att-map quarter; qt==0 context+FC
//   wg[192..207] input-stats rider: partials -> cnt_s barrier -> factors
//                -> flag_norm[b]
__global__ __attribute__((amdgpu_waves_per_eu(2, 2))) __launch_bounds__(512)
void megascan(const float* __restrict__ x,
              const float* __restrict__ Wih, const float* __restrict__ Whh,
              const float* __restrict__ bih, const float* __restrict__ bhh,
              const float* __restrict__ proj_x_w, const float* __restrict__ proj_x_b,
              const float* __restrict__ proj_h_w, const float* __restrict__ proj_h_b,
              const float* __restrict__ attn_w,
              const float* __restrict__ fc_w, const float* __restrict__ fc_b,
              float* __restrict__ mu_bd, float* __restrict__ invn,
              float* __restrict__ psumB, float* __restrict__ psqB,
              float* __restrict__ h_glob,        // [L][B][T][H]; layer0 becomes ph
              float* __restrict__ ring,          // [4][B][4][C_][G]
              float* __restrict__ px,            // [B][T][H]
              float* __restrict__ mu_px, float* __restrict__ inv_px,
              float* __restrict__ mu_ln, float* __restrict__ inv_ln,
              float* __restrict__ lsc,           // [B][T]
              float* __restrict__ out, float* __restrict__ out_att,
              int* __restrict__ flag_h,          // [4][B]
              int* __restrict__ flag_g,          // [4][B]
              int* __restrict__ flag_px,         // [B]
              int* __restrict__ flag_ln,         // [B]
              int* __restrict__ cnt,             // [B]
              int* __restrict__ flag_norm,       // [B]
              int* __restrict__ cnt_s) {         // [1]
    const int wg = blockIdx.x;
    const int tid = threadIdx.x;
    __shared__ __align__(16) float shbuf[16 * HROW_];   // scan/rider roles
    __shared__ __align__(16) float sAs[64][32];         // score role
    __shared__ __align__(16) float sBs[32][132];
    __shared__ float sred[64][33];
    __shared__ float stmp[256], swsh[256], sctx[512];
    __shared__ float smu[128], siv[128];

    if (wg < 32) {
        // ======== recurrent consumer (l, batch pair) ========
        // Two independent b-streams share the same Whh registers; each
        // barrier round advances BOTH streams one step -> per-step barrier
        // overhead halves and the two dependency chains hide each other's
        // latency tails.
        const int r = tid >> 2, q = tid & 3;
        const int l = wg >> 3, p = wg & 7;
        const int b0 = p * 2, b1 = p * 2 + 1;
        f4v w0[8], w1[8], w2[8], w3[8];
        const float* wl = Whh + (size_t)l * G_ * 128;
        LOAD_W8(w0, wl + ((size_t)(0 * 128 + r)) * 128 + q * 32);
        LOAD_W8(w1, wl + ((size_t)(1 * 128 + r)) * 128 + q * 32);
        LOAD_W8(w2, wl + ((size_t)(2 * 128 + r)) * 128 + q * 32);
        LOAD_W8(w3, wl + ((size_t)(3 * 128 + r)) * 128 + q * 32);
        float cA = 0.f, cB = 0.f;
        if (tid < 288) { shbuf[tid] = 0.f; shbuf[288 + tid] = 0.f; }  // rows 0..3
        const float* rsA = ring + ((size_t)l * 16 + b0) * (4 * C_ * G_);
        const float* rsB = ring + ((size_t)l * 16 + b1) * (4 * C_ * G_);
        float* hoA = h_glob + ((size_t)l * 16 + b0) * T_ * 128;
        float* hoB = h_glob + ((size_t)l * 16 + b1) * T_ * 128;
        int* fgA = flag_g + l * 16 + b0;
        int* fgB = flag_g + l * 16 + b1;
        int* fhA = flag_h + l * 16 + b0;
        int* fhB = flag_h + l * 16 + b1;
        __syncthreads();

#pragma unroll 1
        for (int k = 0; k < NCHUNK_; k++) {
            if (tid == 0) { wait_ge_(fgA, k + 1); wait_ge_(fgB, k + 1); }
            __syncthreads();
            const float* gA = rsA + (size_t)(k & 3) * C_ * G_;
            const float* gB = rsB + (size_t)(k & 3) * C_ * G_;
            float* hsA = hoA + (size_t)k * C_ * 128 + r;
            float* hsB = hoB + (size_t)k * C_ * 128 + r;
            // prefetch: pc = steps 0,1 ; pn = steps 2,3 (per stream)
            float pcA[8], pnA[8], pcB[8], pnB[8];
            RING_LD8(pcA, gA);
            RING_LD8(pcB, gB);
            RING_LD8(pnA, gA + 2 * G_);
            RING_LD8(pnB, gB + 2 * G_);
#pragma unroll 1
            for (int u = 0; u < 8; u++) {
                float nnA[8], nnB[8];
                if (u < 6) {   // prefetch steps 2u+4, 2u+5 (consumed at iter u+2)
                    RING_LD8(nnA, gA + (size_t)(2 * u + 4) * G_);
                    RING_LD8(nnB, gB + (size_t)(2 * u + 4) * G_);
                } else {
#pragma unroll
                    for (int j = 0; j < 8; j++) { nnA[j] = 0.f; nnB[j] = 0.f; }
                }
                // even step (read buf0, write buf1) for both streams, 1 barrier
                REC_STEP2(0, 0, 1, pcA[0], pcA[1], pcA[2], pcA[3], cA, hsA)
                REC_STEP2(1, 0, 1, pcB[0], pcB[1], pcB[2], pcB[3], cB, hsB)
                __syncthreads();
                // odd step (read buf1, write buf0) for both streams, 1 barrier
                REC_STEP2(0, 1, 0, pcA[4], pcA[5], pcA[6], pcA[7], cA, hsA)
                REC_STEP2(1, 1, 0, pcB[4], pcB[5], pcB[6], pcB[7], cB, hsB)
#pragma unroll
                for (int j = 0; j < 8; j++) {
                    pcA[j] = pnA[j]; pnA[j] = nnA[j];
                    pcB[j] = pnB[j]; pnB[j] = nnB[j];
                }
                __syncthreads();
            }
            // last barrier drained each wave's vmcnt: all h stores of this
            // chunk are L2-visible before the releases.
            if (tid == 0) {
                __hip_atomic_store(fhA, k + 1, __ATOMIC_RELEASE, __HIP_MEMORY_SCOPE_AGENT);
                __hip_atomic_store(fhB, k + 1, __ATOMIC_RELEASE, __HIP_MEMORY_SCOPE_AGENT);
            }
        }
    } else if (wg < 96) {
        // ======== xproj producer (layers 0..3) ========
        const int r = tid >> 2, q = tid & 3;
        const int l = (wg - 32) >> 4, b = (wg - 32) & 15;
        f4v w0[8], w1[8], w2[8], w3[8];
        const float* wl = Wih + (size_t)l * G_ * 128;
        LOAD_W8(w0, wl + ((size_t)(0 * 128 + r)) * 128 + q * 32);
        LOAD_W8(w1, wl + ((size_t)(1 * 128 + r)) * 128 + q * 32);
        LOAD_W8(w2, wl + ((size_t)(2 * 128 + r)) * 128 + q * 32);
        LOAD_W8(w3, wl + ((size_t)(3 * 128 + r)) * 128 + q * 32);
        float bs0 = bih[l * G_ + r] + bhh[l * G_ + r];
        float bs1 = bih[l * G_ + 128 + r] + bhh[l * G_ + 128 + r];
        float bs2 = bih[l * G_ + 256 + r] + bhh[l * G_ + 256 + r];
        float bs3 = bih[l * G_ + 384 + r] + bhh[l * G_ + 384 + r];
        const float* hsrc = (l > 0) ? h_glob + ((size_t)(l - 1) * 16 + b) * T_ * 128
                                    : x + (size_t)b * T_ * 128;
        float muk = 0.f, ivk = 1.f;
        if (l == 0) {
            if (tid == 0) wait_ge_(flag_norm + b, 1);
            __syncthreads();                       // acquire L1-inv CU-wide
            muk = mu_bd[b * 128 + (tid & 127)];    // plain after acquire
            ivk = invn[b * 128 + (tid & 127)];
        }
        float* rout = ring + ((size_t)l * 16 + b) * (4 * C_ * G_);
        int* fhp = (l > 0) ? flag_h + (l - 1) * 16 + b : flag_h;
        int* fhme = flag_h + l * 16 + b;
        int* fgo = flag_g + l * 16 + b;

#pragma unroll 1
        for (int k = 0; k < NCHUNK_; k++) {
            if (tid == 0) {
                if (l > 0) wait_ge_(fhp, k + 1);
                if (k >= 4) wait_ge_(fhme, k - 3);
            }
            __syncthreads();
#pragma unroll
            for (int i = 0; i < 4; i++) {
                int idx = i * 512 + tid;
                float v;
                if (l == 0) {
                    v = hsrc[(size_t)k * C_ * 128 + idx];
                    v = (v - muk) * ivk;
                } else {
                    v = ald_(hsrc + (size_t)k * C_ * 128 + idx);
                }
                shbuf[(idx >> 7) * HROW_ + HOFF(idx & 127)] = v;
            }
            __syncthreads();
#pragma unroll 4
            for (int s = 0; s < C_; s++) {
                const f4v* hb4 = (const f4v*)(shbuf + s * HROW_ + q * 36);
                f4v hv[8];
#pragma unroll
                for (int j = 0; j < 8; j++) hv[j] = hb4[j];
                float z0, z1, z2, z3;
                DOT32R(z0, w0, hv);
                DOT32R(z1, w1, hv);
                DOT32R(z2, w2, hv);
                DOT32R(z3, w3, hv);
                z0 += __shfl_xor(z0, 1); z0 += __shfl_xor(z0, 2);
                z1 += __shfl_xor(z1, 1); z1 += __shfl_xor(z1, 2);
                z2 += __shfl_xor(z2, 1); z2 += __shfl_xor(z2, 2);
                z3 += __shfl_xor(z3, 1); z3 += __shfl_xor(z3, 2);
                if (q == 0) {
                    float* ro = rout + ((size_t)(k & 3) * C_ + s) * G_;
                    ast_(ro + r, z0 + bs0);
                    ast_(ro + 128 + r, z1 + bs1);
                    ast_(ro + 256 + r, z2 + bs2);
                    ast_(ro + 384 + r, z3 + bs3);
                }
            }
            __syncthreads();
            if (tid == 0) __hip_atomic_store(fgo, k + 1, __ATOMIC_RELEASE, __HIP_MEMORY_SCOPE_AGENT);
        }
    } else if (wg < 112) {
        // ======== px rider: px[b] = norm(x[b]) @ proj_x_w^T + b; + IN stats ========
        const int b = wg - 96;
        const int h = tid & 127, tq = tid >> 7;
        f4v w0[8], w1[8], w2[8], w3[8];
        LOAD_W8(w0, proj_x_w + (size_t)h * 128 + 0);
        LOAD_W8(w1, proj_x_w + (size_t)h * 128 + 32);
        LOAD_W8(w2, proj_x_w + (size_t)h * 128 + 64);
        LOAD_W8(w3, proj_x_w + (size_t)h * 128 + 96);
        float bsx = proj_x_b[h];
        if (tid == 0) wait_ge_(flag_norm + b, 1);
        __syncthreads();
        float muk = mu_bd[b * 128 + h], ivk = invn[b * 128 + h];   // plain after acquire
        const float* xb = x + (size_t)b * T_ * 128;
        float* pxb = px + (size_t)b * T_ * 128;
        float sacc = 0.f, qacc = 0.f;

        for (int blk = 0; blk < 16; blk++) {
            int t0 = blk * 16;
            __syncthreads();
#pragma unroll
            for (int j = 0; j < 4; j++) {
                int tt = tq * 4 + j;
                float v = xb[(size_t)(t0 + tt) * 128 + h];
                shbuf[tt * HROW_ + HOFF(h)] = (v - muk) * ivk;
            }
            __syncthreads();
#pragma unroll
            for (int j = 0; j < 4; j++) {
                int tt = tq * 4 + j;
                const float* row = shbuf + tt * HROW_;
                f4v hv[8];
                float p0, p1, p2, p3;
                const f4v* r4 = (const f4v*)(row + 0 * 36);
#pragma unroll
                for (int u = 0; u < 8; u++) hv[u] = r4[u];
                DOT32R(p0, w0, hv);
                r4 = (const f4v*)(row + 1 * 36);
#pragma unroll
                for (int u = 0; u < 8; u++) hv[u] = r4[u];
                DOT32R(p1, w1, hv);
                r4 = (const f4v*)(row + 2 * 36);
#pragma unroll
                for (int u = 0; u < 8; u++) hv[u] = r4[u];
                DOT32R(p2, w2, hv);
                r4 = (const f4v*)(row + 3 * 36);
#pragma unroll
                for (int u = 0; u < 8; u++) hv[u] = r4[u];
                DOT32R(p3, w3, hv);
                float val = (p0 + p1) + (p2 + p3) + bsx;
                ast_(pxb + (size_t)(t0 + tt) * 128 + h, val);
                sacc += val; qacc += val * val;
            }
        }
        __syncthreads();
        shbuf[tq * 128 + h] = sacc;
        shbuf[512 + tq * 128 + h] = qacc;
        __syncthreads();
        if (tq == 0) {
            float s = shbuf[h] + shbuf[128 + h] + shbuf[256 + h] + shbuf[384 + h];
            float qq = shbuf[512 + h] + shbuf[640 + h] + shbuf[768 + h] + shbuf[896 + h];
            float m = s * (1.f / T_);
            float v = qq * (1.f / T_) - m * m;
            ast_(mu_px + b * 128 + h, m);
            ast_(inv_px + b * 128 + h, rsqrtf(fmaxf(v, 0.f) + EPS_));
        }
        __syncthreads();   // drains vmcnt: px + stats visible
        if (tid == 0) __hip_atomic_store(flag_px + b, 1, __ATOMIC_RELEASE, __HIP_MEMORY_SCOPE_AGENT);
    } else if (wg < 128) {
        // ======== h3-stats rider: IN stats of layer-3 h, chunk-incremental ========
        const int b = wg - 112;
        const int h = tid & 127, st = tid >> 7;
        const float* hsrc = h_glob + ((size_t)3 * 16 + b) * T_ * 128;
        int* f3 = flag_h + 3 * 16 + b;
        float s = 0.f, q = 0.f;
        for (int k = 0; k < NCHUNK_; k++) {
            if (tid == 0) wait_ge_(f3, k + 1);
            __syncthreads();
#pragma unroll
            for (int j = 0; j < 4; j++) {
                int tt = st * 4 + j;
                float v = ald_(hsrc + (size_t)(k * C_ + tt) * 128 + h);
                s += v; q += v * v;
            }
        }
        shbuf[st * 128 + h] = s;
        shbuf[512 + st * 128 + h] = q;
        __syncthreads();
        if (st == 0) {
            float ss = shbuf[h] + shbuf[128 + h] + shbuf[256 + h] + shbuf[384 + h];
            float qq = shbuf[512 + h] + shbuf[640 + h] + shbuf[768 + h] + shbuf[896 + h];
            float m = ss * (1.f / T_);
            float v = qq * (1.f / T_) - m * m;
            ast_(mu_ln + b * 128 + h, m);
            ast_(inv_ln + b * 128 + h, rsqrtf(fmaxf(v, 0.f) + EPS_));
        }
        __syncthreads();   // drains vmcnt
        if (tid == 0) __hip_atomic_store(flag_ln + b, 1, __ATOMIC_RELEASE, __HIP_MEMORY_SCOPE_AGENT);
    } else if (wg < 192) {
        // ======== score/tail rider: blk in [0,64), b = blk>>2, qt = blk&3 ========
        const int blk = wg - 128;
        const int b = blk >> 2, qt = blk & 3;
        const int m0 = qt * 64;                  // t-row offset within batch
        if (tid == 0) { wait_ge_(flag_px + b, 1); wait_ge_(flag_ln + b, 1); }
        __syncthreads();                          // acquire L1-inv applied CU-wide
        if (tid < 128) {                          // stage norm factors (plain loads)
            smu[tid] = mu_px[b * 128 + tid];
            siv[tid] = inv_px[b * 128 + tid];
        }
        __syncthreads();

        const float* h3b = h_glob + ((size_t)3 * 16 + b) * T_ * 128;
        float* phg = h_glob;                      // ph aliases layer-0 h (all readers done)
        const int lr = tid >> 3, lc = (tid & 7) << 2;   // A staging
        const int nB = tid >> 2, k0B = (tid & 3) << 3;  // B staging
        const int tm = (tid >> 5) << 2, tn = (tid & 31) << 2;
        float acc[4][4] = {};
        const float* mup = mu_ln + b * 128;
        const float* ivp = inv_ln + b * 128;
        for (int kb = 0; kb < 128; kb += 32) {
            float4 av = *(const float4*)(h3b + (size_t)(m0 + lr) * 128 + kb + lc);
            float4 m4 = *(const float4*)(mup + kb + lc);
            float4 i4 = *(const float4*)(ivp + kb + lc);
            av.x = (av.x - m4.x) * i4.x; av.y = (av.y - m4.y) * i4.y;
            av.z = (av.z - m4.z) * i4.z; av.w = (av.w - m4.w) * i4.w;
            float4 bv0 = *(const float4*)(proj_h_w + (size_t)nB * 128 + kb + k0B);
            float4 bv1 = *(const float4*)(proj_h_w + (size_t)nB * 128 + kb + k0B + 4);
            __syncthreads();
            *(float4*)&sAs[lr][lc] = av;
            sBs[k0B + 0][nB] = bv0.x; sBs[k0B + 1][nB] = bv0.y;
            sBs[k0B + 2][nB] = bv0.z; sBs[k0B + 3][nB] = bv0.w;
            sBs[k0B + 4][nB] = bv1.x; sBs[k0B + 5][nB] = bv1.y;
            sBs[k0B + 6][nB] = bv1.z; sBs[k0B + 7][nB] = bv1.w;
            __syncthreads();
#pragma unroll
            for (int k4 = 0; k4 < 8; k4++) {
                f4v a4[4];
#pragma unroll
                for (int i = 0; i < 4; i++) a4[i] = *(const f4v*)&sAs[tm + i][k4 * 4];
#pragma unroll
                for (int kk = 0; kk < 4; kk++) {
                    f4v b4 = *(const f4v*)&sBs[k4 * 4 + kk][tn];
#pragma unroll
                    for (int i = 0; i < 4; i++) {
                        acc[i][0] = fmaf(a4[i][kk], b4.x, acc[i][0]);
                        acc[i][1] = fmaf(a4[i][kk], b4.y, acc[i][1]);
                        acc[i][2] = fmaf(a4[i][kk], b4.z, acc[i][2]);
                        acc[i][3] = fmaf(a4[i][kk], b4.w, acc[i][3]);
                    }
                }
            }
        }
        // epilogue: ph + score partials (vectorized plain px read; LDS factors)
        float spart[4];
#pragma unroll
        for (int i = 0; i < 4; i++) {
            int t = m0 + tm + i;
            size_t prow = ((size_t)b * 256 + t) * 128;
            f4v pxv = *(const f4v*)(px + prow + tn);
            float sp = 0.f;
#pragma unroll
            for (int j = 0; j < 4; j++) {
                int col = tn + j;
                float val = acc[i][j] + proj_h_b[col];
                ast_(phg + prow + col, val);
                float inx = (pxv[j] - smu[col]) * siv[col];
                sp = fmaf(tanh_(val + inx), attn_w[col], sp);
            }
            spart[i] = sp;
        }
        __syncthreads();
#pragma unroll
        for (int i = 0; i < 4; i++) sred[tm + i][tid & 31] = spart[i];
        __syncthreads();
        if (tid < 64) {
            float s = 0.f;
#pragma unroll
            for (int j = 0; j < 32; j++) s += sred[tid][j];
            ast_(lsc + b * 256 + m0 + tid, s);
        }
        __syncthreads();   // drains vmcnt: ph + lsc visible
        if (tid == 0) {
            (void)__hip_atomic_fetch_add(cnt + b, 1, __ATOMIC_ACQ_REL, __HIP_MEMORY_SCOPE_AGENT);
            wait_ge_(cnt + b, 4);
        }
        __syncthreads();
        // softmax over lsc[b][0..255] (redundant per block, cheap; plain loads OK)
        float v = 0.f;
        if (tid < 256) { v = lsc[b * 256 + tid]; stmp[tid] = v; }
        __syncthreads();
        for (int off = 128; off > 0; off >>= 1) {
            if (tid < off) stmp[tid] = fmaxf(stmp[tid], stmp[tid + off]);
            __syncthreads();
        }
        float mx = stmp[0];
        __syncthreads();
        float e = (tid < 256) ? __expf(v - mx) : 0.f;
        if (tid < 256) stmp[tid] = e;
        __syncthreads();
        for (int off = 128; off > 0; off >>= 1) {
            if (tid < off) stmp[tid] += stmp[tid + off];
            __syncthreads();
        }
        float tot = stmp[0];
        __syncthreads();
        if (tid < 256) swsh[tid] = e / tot;
        __syncthreads();
        {   // attention-map quarter (alpha = softmax_t / D, constant across d)
            float* ob = out_att + (size_t)b * T_ * D_ + (size_t)m0 * 128;
            const float invD = 1.f / (float)D_;
            for (int i = tid; i < 64 * 128; i += 512)
                ob[i] = swsh[m0 + (i >> 7)] * invD;
        }
        if (qt == 0) {   // context + FC
            int h = tid & 127, st = tid >> 7;
            float a = 0.f;
            for (int tt = st * 64; tt < st * 64 + 64; tt++)
                a = fmaf(phg[((size_t)b * 256 + tt) * 128 + h], swsh[tt], a);
            sctx[st * 128 + h] = a;
            __syncthreads();
            if (tid < 128) sctx[tid] = sctx[tid] + sctx[128 + tid] + sctx[256 + tid] + sctx[384 + tid];
            __syncthreads();
            if (tid < NC_) {
                float s = fc_b[tid];
                const float* fw = fc_w + tid * 128;
                for (int k = 0; k < 128; k++) s = fmaf(sctx[k], fw[k], s);
                out[b * NC_ + tid] = s;
            }
        }
    } else {
        // ======== input-stats rider: b = wg - 192 ========
        const int b = wg - 192;
        const int d = tid & 127, r = tid >> 7;
        const float* xb = x + (size_t)b * T_ * 128;
        float s = 0.f, q = 0.f;
        for (int t = r; t < T_; t += 4) {
            float v = xb[(size_t)t * 128 + d];
            s += v; q += v * v;
        }
        shbuf[tid] = s; shbuf[512 + tid] = q;
        __syncthreads();
        if (r == 0) {
            s = shbuf[d] + shbuf[128 + d] + shbuf[256 + d] + shbuf[384 + d];
            q = shbuf[512 + d] + shbuf[640 + d] + shbuf[768 + d] + shbuf[896 + d];
            ast_(psumB + b * 128 + d, s);
            ast_(psqB + b * 128 + d, q);
        }
        __syncthreads();   // drains vmcnt: partials visible
        if (tid == 0) {
            (void)__hip_atomic_fetch_add(cnt_s, 1, __ATOMIC_ACQ_REL, __HIP_MEMORY_SCOPE_AGENT);
            wait_ge_(cnt_s, 16);
        }
        __syncthreads();   // acquire L1-inv applied CU-wide
        if (tid < 128) {
            float S = 0.f, Q = 0.f, sb = 0.f, qb = 0.f;
            for (int bb = 0; bb < 16; bb++) {
                float ps = psumB[bb * 128 + tid];   // plain after acquire
                float pq = psqB[bb * 128 + tid];
                S += ps; Q += pq;
                if (bb == b) { sb = ps; qb = pq; }
            }
            float n = (float)(B_ * T_);
            float m = S / n;
            float varu = (Q - n * m * m) / (n - 1.f);
            float sd = sqrtf(fmaxf(varu, 0.f)) + EPS_;
            float mu = sb * (1.f / T_);
            float varT = qb * (1.f / T_) - mu * mu;
            ast_(mu_bd + b * 128 + tid, mu);
            ast_(invn + b * 128 + tid, rsqrtf(fmaxf(varT, 0.f) + EPS_ * sd * sd));
        }
        __syncthreads();   // drains vmcnt: factors visible
        if (tid == 0) __hip_atomic_store(flag_norm + b, 1, __ATOMIC_RELEASE, __HIP_MEMORY_SCOPE_AGENT);
    }
}

// ---------------- launcher ----------------
extern "C" void kernel_launch(void* const* d_in, const int* in_sizes, int n_in,
                              void* d_out, int out_size, void* d_ws, size_t ws_size,
                              hipStream_t stream) {
    const float* x        = (const float*)d_in[0];
    const float* Wih      = (const float*)d_in[1];
    const float* Whh      = (const float*)d_in[2];
    const float* bih      = (const float*)d_in[3];
    const float* bhh      = (const float*)d_in[4];
    const float* proj_h_w = (const float*)d_in[5];
    const float* proj_h_b = (const float*)d_in[6];
    const float* proj_x_w = (const float*)d_in[7];
    const float* proj_x_b = (const float*)d_in[8];
    const float* attn_w   = (const float*)d_in[9];
    const float* fc_w     = (const float*)d_in[10];
    const float* fc_b     = (const float*)d_in[11];
    float* out = (float*)d_out;

    float* ws = (float*)d_ws;
    const size_t NTD = (size_t)B_ * T_ * D_;       // 524288
    float* h_glob = ws;                            // 4*NTD
    float* ring   = h_glob + 4 * NTD;              // 4*NTD
    float* px     = ring + 4 * NTD;                // 1*NTD
    float* smalls = px + NTD;
    float* psumB  = smalls;                        // 16*128
    float* psqB   = psumB + 2048;                  // 16*128
    float* mu_bd  = psqB + 2048;
    float* invn   = mu_bd + 2048;
    float* mu_ln  = invn + 2048;
    float* inv_ln = mu_ln + 2048;
    float* mu_px  = inv_ln + 2048;
    float* inv_px = mu_px + 2048;
    float* lsc    = inv_px + 2048;
    int*   flags  = (int*)(lsc + 4096);
    int*   flag_h   = flags;                       // [64]
    int*   flag_g   = flags + 64;                  // [64]
    int*   flag_px  = flags + 128;                 // [16]
    int*   flag_ln  = flags + 144;                 // [16]
    int*   cnt      = flags + 160;                 // [16]
    int*   flag_norm= flags + 176;                 // [16]
    int*   cnt_s    = flags + 192;                 // [1]

    hipMemsetAsync((void*)flags, 0, 256 * sizeof(int), stream);

    // single fused dispatch: stats + 4-layer LSTM pipeline + all riders + tail
    megascan<<<208, 512, 0, stream>>>(x, Wih, Whh, bih, bhh,
                                      proj_x_w, proj_x_b, proj_h_w, proj_h_b,
                                      attn_w, fc_w, fc_b,
                                      mu_bd, invn, psumB, psqB,
                                      h_glob, ring, px,
                                      mu_px, inv_px, mu_ln, inv_ln,
                                      lsc, out, out + B_ * NC_,
                                      flag_h, flag_g, flag_px, flag_ln, cnt,
                                      flag_norm, cnt_s);
}

// Round 3
// 455.370 us; speedup vs baseline: 1.6342x; 1.6342x over previous
//
#include <hip/hip_runtime.h>
#include <math.h>
#include <cstddef>

#define B_ 16
#define T_ 256
#define D_ 128
#define H_ 128
#define L_ 4
#define G_ 512          // 4*H
#define NC_ 10
#define EPS_ 1e-5f
#define C_ 16           // pipeline chunk (timesteps per flag)
#define NCHUNK_ (T_ / C_)

// padded LDS row: +4 floats per 32 -> 144-float rows; quarter q at q*36 floats
#define HROW_ 144
#define HOFF(k) ((k) + (((k) >> 5) << 2))

typedef float f4v __attribute__((ext_vector_type(4)));

// 8 x global_load_dwordx4 -> 32 floats resident (compiler cannot remat asm)
#define LOAD_W8(w, base)                                                   \
    asm volatile(                                                          \
        "global_load_dwordx4 %0, %8, off\n\t"                             \
        "global_load_dwordx4 %1, %8, off offset:16\n\t"                   \
        "global_load_dwordx4 %2, %8, off offset:32\n\t"                   \
        "global_load_dwordx4 %3, %8, off offset:48\n\t"                   \
        "global_load_dwordx4 %4, %8, off offset:64\n\t"                   \
        "global_load_dwordx4 %5, %8, off offset:80\n\t"                   \
        "global_load_dwordx4 %6, %8, off offset:96\n\t"                   \
        "global_load_dwordx4 %7, %8, off offset:112\n\t"                  \
        "s_waitcnt vmcnt(0)"                                               \
        : "=&v"(w[0]), "=&v"(w[1]), "=&v"(w[2]), "=&v"(w[3]),              \
          "=&v"(w[4]), "=&v"(w[5]), "=&v"(w[6]), "=&v"(w[7])               \
        : "v"(base)                                                        \
        : "memory")

// 32-k partial dot against pre-loaded h registers (params avoid x/y/z/w tokens)
#define DOT32R(dst_, warr_, hvarr_)                                        \
    {                                                                      \
        float d0_ = 0.f, d1_ = 0.f;                                        \
        _Pragma("unroll")                                                  \
        for (int j_ = 0; j_ < 8; j_++) {                                   \
            d0_ = fmaf(warr_[j_].x, hvarr_[j_].x, d0_);                    \
            d1_ = fmaf(warr_[j_].y, hvarr_[j_].y, d1_);                    \
            d0_ = fmaf(warr_[j_].z, hvarr_[j_].z, d0_);                    \
            d1_ = fmaf(warr_[j_].w, hvarr_[j_].w, d1_);                    \
        }                                                                  \
        dst_ = d0_ + d1_;                                                  \
    }

// lgkm-only barrier: orders LDS writes->reads WITHOUT draining vmcnt, so the
// per-step global h store and the ring prefetch loads stay in flight across
// step barriers (drained once per chunk by the full __syncthreads before the
// flag release).
#define LGKM_BAR_ asm volatile("s_waitcnt lgkmcnt(0)\n\ts_barrier" ::: "memory")

// ---------------- device helpers ----------------
__device__ __forceinline__ float sigmoid_(float x) {
    x = fminf(fmaxf(x, -30.f), 30.f);
    return 1.f / (1.f + __expf(-x));
}
__device__ __forceinline__ float tanh_(float x) {
    float ax = fminf(fabsf(x), 15.f);
    float e = __expf(2.f * ax);
    float t = 1.f - 2.f / (e + 1.f);
    return copysignf(t, x);
}
// quad reduce via DPP quad_perm (pure VALU, no LDS pipe, no lgkm wait).
// Bit-identical add order to the old __shfl_xor(1) then __shfl_xor(2).
__device__ __forceinline__ float qsum4_(float z) {
    int a = __builtin_amdgcn_update_dpp(0, __float_as_int(z), 0xB1, 0xF, 0xF, true); // quad_perm [1,0,3,2]
    z += __int_as_float(a);
    int b = __builtin_amdgcn_update_dpp(0, __float_as_int(z), 0x4E, 0xF, 0xF, true); // quad_perm [2,3,0,1]
    z += __int_as_float(b);
    return z;
}
__device__ __forceinline__ void wait_ge_(int* p, int v) {
    if (__hip_atomic_load(p, __ATOMIC_RELAXED, __HIP_MEMORY_SCOPE_AGENT) < v) {
        do { __builtin_amdgcn_s_sleep(1); }
        while (__hip_atomic_load(p, __ATOMIC_RELAXED, __HIP_MEMORY_SCOPE_AGENT) < v);
    }
    (void)__hip_atomic_load(p, __ATOMIC_ACQUIRE, __HIP_MEMORY_SCOPE_AGENT);
}
__device__ __forceinline__ void ast_(float* p, float v) {
    __hip_atomic_store(p, v, __ATOMIC_RELAXED, __HIP_MEMORY_SCOPE_AGENT);
}
__device__ __forceinline__ float ald_(const float* p) {
    return __hip_atomic_load(p, __ATOMIC_RELAXED, __HIP_MEMORY_SCOPE_AGENT);
}

// one LSTM timestep: read h from LDS buf RD, write h to LDS buf WR,
// per-step global h store from q==0 lanes; ends with lgkm-only barrier.
#define REC_STEP(RD, WR, PI, PF, PG, PO)                                   \
    {                                                                      \
        const f4v* hb4_ = (const f4v*)(shbuf + (RD) * HROW_ + q * 36);     \
        f4v hv[8];                                                         \
        _Pragma("unroll")                                                  \
        for (int jj_ = 0; jj_ < 8; jj_++) hv[jj_] = hb4_[jj_];             \
        float zi, zf, zg, zo;                                              \
        DOT32R(zi, w0, hv);                                                \
        DOT32R(zf, w1, hv);                                                \
        DOT32R(zg, w2, hv);                                                \
        DOT32R(zo, w3, hv);                                                \
        zi = qsum4_(zi) + (PI); zf = qsum4_(zf) + (PF);                    \
        zg = qsum4_(zg) + (PG); zo = qsum4_(zo) + (PO);                    \
        float ai = sigmoid_(zi), af = sigmoid_(zf);                        \
        float ag = tanh_(zg),    ao = sigmoid_(zo);                        \
        c = fmaf(af, c, ai * ag);                                          \
        float hn = ao * tanh_(c);                                          \
        if (q == 0) {                                                      \
            shbuf[(WR) * HROW_ + HOFF(r)] = hn;                            \
            ast_(hst, hn);                                                 \
        }                                                                  \
        hst += 128;                                                        \
        LGKM_BAR_;                                                         \
    }

// ---------------- megascan: EVERYTHING (stats + scan + riders + score/tail) -------
// 240 WGs x 512 thr (waves_per_eu(2,2) => 1 WG/CU cap => all 240 co-resident):
//   wg[0..63]    rec(l,b)
//   wg[64..127]  xproj(l=0..3,b): l==0 waits flag_norm[b] for factors
//   wg[128..143] px rider (waits flag_norm[b]) -> flag_px[b]
//   wg[144..159] h3-stats rider -> flag_ln[b]
//   wg[160..223] score/tail rider (4/batch): ph GEMM + scores; cnt sync;
//                softmax + att-map quarter; qt==0 context+FC
//   wg[224..239] input-stats rider: partials -> cnt_s barrier -> factors
//                -> flag_norm[b]
__global__ __attribute__((amdgpu_waves_per_eu(2, 2))) __launch_bounds__(512)
void megascan(const float* __restrict__ x,
              const float* __restrict__ Wih, const float* __restrict__ Whh,
              const float* __restrict__ bih, const float* __restrict__ bhh,
              const float* __restrict__ proj_x_w, const float* __restrict__ proj_x_b,
              const float* __restrict__ proj_h_w, const float* __restrict__ proj_h_b,
              const float* __restrict__ attn_w,
              const float* __restrict__ fc_w, const float* __restrict__ fc_b,
              float* __restrict__ mu_bd, float* __restrict__ invn,
              float* __restrict__ psumB, float* __restrict__ psqB,
              float* __restrict__ h_glob,        // [L][B][T][H]; layer0 becomes ph
              float* __restrict__ ring,          // [4][B][4][C_][G]
              float* __restrict__ px,            // [B][T][H]
              float* __restrict__ mu_px, float* __restrict__ inv_px,
              float* __restrict__ mu_ln, float* __restrict__ inv_ln,
              float* __restrict__ lsc,           // [B][T]
              float* __restrict__ out, float* __restrict__ out_att,
              int* __restrict__ flag_h,          // [4][B]
              int* __restrict__ flag_g,          // [4][B]
              int* __restrict__ flag_px,         // [B]
              int* __restrict__ flag_ln,         // [B]
              int* __restrict__ cnt,             // [B]
              int* __restrict__ flag_norm,       // [B]
              int* __restrict__ cnt_s) {         // [1]
    const int wg = blockIdx.x;
    const int tid = threadIdx.x;
    __shared__ __align__(16) float shbuf[16 * HROW_];   // scan/rider roles
    __shared__ __align__(16) float sAs[64][32];         // score role
    __shared__ __align__(16) float sBs[32][132];
    __shared__ float sred[64][33];
    __shared__ float stmp[256], swsh[256], sctx[512];
    __shared__ float smu[128], siv[128];

    if (wg < 64) {
        // ======== recurrent consumer (l, b) ========
        // Rolled 2-step body + named-register ring prefetch at distance-2
        // steps + per-step global h stores + lgkm-only step barriers.
        const int r = tid >> 2, q = tid & 3;
        const int l = wg >> 4, b = wg & 15;
        f4v w0[8], w1[8], w2[8], w3[8];
        const float* wl = Whh + (size_t)l * G_ * 128;
        LOAD_W8(w0, wl + ((size_t)(0 * 128 + r)) * 128 + q * 32);
        LOAD_W8(w1, wl + ((size_t)(1 * 128 + r)) * 128 + q * 32);
        LOAD_W8(w2, wl + ((size_t)(2 * 128 + r)) * 128 + q * 32);
        LOAD_W8(w3, wl + ((size_t)(3 * 128 + r)) * 128 + q * 32);
        float c = 0.f;
        if (tid < HROW_) shbuf[tid] = 0.f;
        const float* rsl = ring + ((size_t)l * 16 + b) * (4 * C_ * G_);
        float* hob = h_glob + ((size_t)l * 16 + b) * T_ * 128;
        int* fg = flag_g + l * 16 + b;
        int* fh = flag_h + l * 16 + b;
        __syncthreads();

#pragma unroll 1
        for (int k = 0; k < NCHUNK_; k++) {
            if (tid == 0) wait_ge_(fg, k + 1);
            __syncthreads();
            const float* gb = rsl + (size_t)(k & 3) * C_ * G_;
            float* hst = hob + (size_t)k * C_ * 128 + r;
            // prefetch steps 0,1 (pc) and 2,3 (pn)
            float pc0 = ald_(gb + r),                pc1 = ald_(gb + 128 + r);
            float pc2 = ald_(gb + 256 + r),          pc3 = ald_(gb + 384 + r);
            float pc4 = ald_(gb + G_ + r),           pc5 = ald_(gb + G_ + 128 + r);
            float pc6 = ald_(gb + G_ + 256 + r),     pc7 = ald_(gb + G_ + 384 + r);
            float pn0 = ald_(gb + 2 * G_ + r),       pn1 = ald_(gb + 2 * G_ + 128 + r);
            float pn2 = ald_(gb + 2 * G_ + 256 + r), pn3 = ald_(gb + 2 * G_ + 384 + r);
            float pn4 = ald_(gb + 3 * G_ + r),       pn5 = ald_(gb + 3 * G_ + 128 + r);
            float pn6 = ald_(gb + 3 * G_ + 256 + r), pn7 = ald_(gb + 3 * G_ + 384 + r);
#pragma unroll 1
            for (int u = 0; u < 8; u++) {
                float nn0 = 0.f, nn1 = 0.f, nn2 = 0.f, nn3 = 0.f;
                float nn4 = 0.f, nn5 = 0.f, nn6 = 0.f, nn7 = 0.f;
                if (u < 6) {   // prefetch steps 2u+4, 2u+5 (consumed at iter u+2)
                    const float* g2 = gb + (size_t)(2 * u + 4) * G_;
                    nn0 = ald_(g2 + r);            nn1 = ald_(g2 + 128 + r);
                    nn2 = ald_(g2 + 256 + r);      nn3 = ald_(g2 + 384 + r);
                    nn4 = ald_(g2 + G_ + r);       nn5 = ald_(g2 + G_ + 128 + r);
                    nn6 = ald_(g2 + G_ + 256 + r); nn7 = ald_(g2 + G_ + 384 + r);
                }
                REC_STEP(0, 1, pc0, pc1, pc2, pc3)   // even step: read buf0
                REC_STEP(1, 0, pc4, pc5, pc6, pc7)   // odd step: read buf1
                pc0 = pn0; pc1 = pn1; pc2 = pn2; pc3 = pn3;
                pc4 = pn4; pc5 = pn5; pc6 = pn6; pc7 = pn7;
                pn0 = nn0; pn1 = nn1; pn2 = nn2; pn3 = nn3;
                pn4 = nn4; pn5 = nn5; pn6 = nn6; pn7 = nn7;
            }
            // full barrier: every wave drains vmcnt (h stores L2-visible)
            // before the release.
            __syncthreads();
            if (tid == 0) __hip_atomic_store(fh, k + 1, __ATOMIC_RELEASE, __HIP_MEMORY_SCOPE_AGENT);
        }
    } else if (wg < 128) {
        // ======== xproj producer (layers 0..3) ========
        const int r = tid >> 2, q = tid & 3;
        const int l = (wg - 64) >> 4, b = (wg - 64) & 15;
        f4v w0[8], w1[8], w2[8], w3[8];
        const float* wl = Wih + (size_t)l * G_ * 128;
        LOAD_W8(w0, wl + ((size_t)(0 * 128 + r)) * 128 + q * 32);
        LOAD_W8(w1, wl + ((size_t)(1 * 128 + r)) * 128 + q * 32);
        LOAD_W8(w2, wl + ((size_t)(2 * 128 + r)) * 128 + q * 32);
        LOAD_W8(w3, wl + ((size_t)(3 * 128 + r)) * 128 + q * 32);
        float bs0 = bih[l * G_ + r] + bhh[l * G_ + r];
        float bs1 = bih[l * G_ + 128 + r] + bhh[l * G_ + 128 + r];
        float bs2 = bih[l * G_ + 256 + r] + bhh[l * G_ + 256 + r];
        float bs3 = bih[l * G_ + 384 + r] + bhh[l * G_ + 384 + r];
        const float* hsrc = (l > 0) ? h_glob + ((size_t)(l - 1) * 16 + b) * T_ * 128
                                    : x + (size_t)b * T_ * 128;
        float muk = 0.f, ivk = 1.f;
        if (l == 0) {
            if (tid == 0) wait_ge_(flag_norm + b, 1);
            __syncthreads();                       // acquire L1-inv CU-wide
            muk = mu_bd[b * 128 + (tid & 127)];    // plain after acquire
            ivk = invn[b * 128 + (tid & 127)];
        }
        float* rout = ring + ((size_t)l * 16 + b) * (4 * C_ * G_);
        int* fhp = (l > 0) ? flag_h + (l - 1) * 16 + b : flag_h;
        int* fhme = flag_h + l * 16 + b;
        int* fgo = flag_g + l * 16 + b;

#pragma unroll 1
        for (int k = 0; k < NCHUNK_; k++) {
            if (tid == 0) {
                if (l > 0) wait_ge_(fhp, k + 1);
                if (k >= 4) wait_ge_(fhme, k - 3);
            }
            __syncthreads();
#pragma unroll
            for (int i = 0; i < 4; i++) {
                int idx = i * 512 + tid;
                float v;
                if (l == 0) {
                    v = hsrc[(size_t)k * C_ * 128 + idx];
                    v = (v - muk) * ivk;
                } else {
                    v = ald_(hsrc + (size_t)k * C_ * 128 + idx);
                }
                shbuf[(idx >> 7) * HROW_ + HOFF(idx & 127)] = v;
            }
            LGKM_BAR_;   // staging visibility only; ring stores stay in flight
#pragma unroll 4
            for (int s = 0; s < C_; s++) {
                const f4v* hb4 = (const f4v*)(shbuf + s * HROW_ + q * 36);
                f4v hv[8];
#pragma unroll
                for (int j = 0; j < 8; j++) hv[j] = hb4[j];
                float z0, z1, z2, z3;
                DOT32R(z0, w0, hv);
                DOT32R(z1, w1, hv);
                DOT32R(z2, w2, hv);
                DOT32R(z3, w3, hv);
                z0 = qsum4_(z0); z1 = qsum4_(z1);
                z2 = qsum4_(z2); z3 = qsum4_(z3);
                if (q == 0) {
                    float* ro = rout + ((size_t)(k & 3) * C_ + s) * G_;
                    ast_(ro + r, z0 + bs0);
                    ast_(ro + 128 + r, z1 + bs1);
                    ast_(ro + 256 + r, z2 + bs2);
                    ast_(ro + 384 + r, z3 + bs3);
                }
            }
            __syncthreads();   // full: drains ring stores before release
            if (tid == 0) __hip_atomic_store(fgo, k + 1, __ATOMIC_RELEASE, __HIP_MEMORY_SCOPE_AGENT);
        }
    } else if (wg < 144) {
        // ======== px rider: px[b] = norm(x[b]) @ proj_x_w^T + b; + IN stats ========
        const int b = wg - 128;
        const int h = tid & 127, tq = tid >> 7;
        f4v w0[8], w1[8], w2[8], w3[8];
        LOAD_W8(w0, proj_x_w + (size_t)h * 128 + 0);
        LOAD_W8(w1, proj_x_w + (size_t)h * 128 + 32);
        LOAD_W8(w2, proj_x_w + (size_t)h * 128 + 64);
        LOAD_W8(w3, proj_x_w + (size_t)h * 128 + 96);
        float bsx = proj_x_b[h];
        if (tid == 0) wait_ge_(flag_norm + b, 1);
        __syncthreads();
        float muk = mu_bd[b * 128 + h], ivk = invn[b * 128 + h];   // plain after acquire
        const float* xb = x + (size_t)b * T_ * 128;
        float* pxb = px + (size_t)b * T_ * 128;
        float sacc = 0.f, qacc = 0.f;

        for (int blk = 0; blk < 16; blk++) {
            int t0 = blk * 16;
            __syncthreads();
#pragma unroll
            for (int j = 0; j < 4; j++) {
                int tt = tq * 4 + j;
                float v = xb[(size_t)(t0 + tt) * 128 + h];
                shbuf[tt * HROW_ + HOFF(h)] = (v - muk) * ivk;
            }
            __syncthreads();
#pragma unroll
            for (int j = 0; j < 4; j++) {
                int tt = tq * 4 + j;
                const float* row = shbuf + tt * HROW_;
                f4v hv[8];
                float p0, p1, p2, p3;
                const f4v* r4 = (const f4v*)(row + 0 * 36);
#pragma unroll
                for (int u = 0; u < 8; u++) hv[u] = r4[u];
                DOT32R(p0, w0, hv);
                r4 = (const f4v*)(row + 1 * 36);
#pragma unroll
                for (int u = 0; u < 8; u++) hv[u] = r4[u];
                DOT32R(p1, w1, hv);
                r4 = (const f4v*)(row + 2 * 36);
#pragma unroll
                for (int u = 0; u < 8; u++) hv[u] = r4[u];
                DOT32R(p2, w2, hv);
                r4 = (const f4v*)(row + 3 * 36);
#pragma unroll
                for (int u = 0; u < 8; u++) hv[u] = r4[u];
                DOT32R(p3, w3, hv);
                float val = (p0 + p1) + (p2 + p3) + bsx;
                ast_(pxb + (size_t)(t0 + tt) * 128 + h, val);
                sacc += val; qacc += val * val;
            }
        }
        __syncthreads();
        shbuf[tq * 128 + h] = sacc;
        shbuf[512 + tq * 128 + h] = qacc;
        __syncthreads();
        if (tq == 0) {
            float s = shbuf[h] + shbuf[128 + h] + shbuf[256 + h] + shbuf[384 + h];
            float qq = shbuf[512 + h] + shbuf[640 + h] + shbuf[768 + h] + shbuf[896 + h];
            float m = s * (1.f / T_);
            float v = qq * (1.f / T_) - m * m;
            ast_(mu_px + b * 128 + h, m);
            ast_(inv_px + b * 128 + h, rsqrtf(fmaxf(v, 0.f) + EPS_));
        }
        __syncthreads();   // drains vmcnt: px + stats visible
        if (tid == 0) __hip_atomic_store(flag_px + b, 1, __ATOMIC_RELEASE, __HIP_MEMORY_SCOPE_AGENT);
    } else if (wg < 160) {
        // ======== h3-stats rider: IN stats of layer-3 h, chunk-incremental ========
        const int b = wg - 144;
        const int h = tid & 127, st = tid >> 7;
        const float* hsrc = h_glob + ((size_t)3 * 16 + b) * T_ * 128;
        int* f3 = flag_h + 3 * 16 + b;
        float s = 0.f, q = 0.f;
        for (int k = 0; k < NCHUNK_; k++) {
            if (tid == 0) wait_ge_(f3, k + 1);
            __syncthreads();
#pragma unroll
            for (int j = 0; j < 4; j++) {
                int tt = st * 4 + j;
                float v = ald_(hsrc + (size_t)(k * C_ + tt) * 128 + h);
                s += v; q += v * v;
            }
        }
        shbuf[st * 128 + h] = s;
        shbuf[512 + st * 128 + h] = q;
        __syncthreads();
        if (st == 0) {
            float ss = shbuf[h] + shbuf[128 + h] + shbuf[256 + h] + shbuf[384 + h];
            float qq = shbuf[512 + h] + shbuf[640 + h] + shbuf[768 + h] + shbuf[896 + h];
            float m = ss * (1.f / T_);
            float v = qq * (1.f / T_) - m * m;
            ast_(mu_ln + b * 128 + h, m);
            ast_(inv_ln + b * 128 + h, rsqrtf(fmaxf(v, 0.f) + EPS_));
        }
        __syncthreads();   // drains vmcnt
        if (tid == 0) __hip_atomic_store(flag_ln + b, 1, __ATOMIC_RELEASE, __HIP_MEMORY_SCOPE_AGENT);
    } else if (wg < 224) {
        // ======== score/tail rider: blk in [0,64), b = blk>>2, qt = blk&3 ========
        const int blk = wg - 160;
        const int b = blk >> 2, qt = blk & 3;
        const int m0 = qt * 64;                  // t-row offset within batch
        if (tid == 0) { wait_ge_(flag_px + b, 1); wait_ge_(flag_ln + b, 1); }
        __syncthreads();                          // acquire L1-inv applied CU-wide
        if (tid < 128) {                          // stage norm factors (plain loads)
            smu[tid] = mu_px[b * 128 + tid];
            siv[tid] = inv_px[b * 128 + tid];
        }
        __syncthreads();

        const float* h3b = h_glob + ((size_t)3 * 16 + b) * T_ * 128;
        float* phg = h_glob;                      // ph aliases layer-0 h (all readers done)
        const int lr = tid >> 3, lc = (tid & 7) << 2;   // A staging
        const int nB = tid >> 2, k0B = (tid & 3) << 3;  // B staging
        const int tm = (tid >> 5) << 2, tn = (tid & 31) << 2;
        float acc[4][4] = {};
        const float* mup = mu_ln + b * 128;
        const float* ivp = inv_ln + b * 128;
        for (int kb = 0; kb < 128; kb += 32) {
            float4 av = *(const float4*)(h3b + (size_t)(m0 + lr) * 128 + kb + lc);
            float4 m4 = *(const float4*)(mup + kb + lc);
            float4 i4 = *(const float4*)(ivp + kb + lc);
            av.x = (av.x - m4.x) * i4.x; av.y = (av.y - m4.y) * i4.y;
            av.z = (av.z - m4.z) * i4.z; av.w = (av.w - m4.w) * i4.w;
            float4 bv0 = *(const float4*)(proj_h_w + (size_t)nB * 128 + kb + k0B);
            float4 bv1 = *(const float4*)(proj_h_w + (size_t)nB * 128 + kb + k0B + 4);
            __syncthreads();
            *(float4*)&sAs[lr][lc] = av;
            sBs[k0B + 0][nB] = bv0.x; sBs[k0B + 1][nB] = bv0.y;
            sBs[k0B + 2][nB] = bv0.z; sBs[k0B + 3][nB] = bv0.w;
            sBs[k0B + 4][nB] = bv1.x; sBs[k0B + 5][nB] = bv1.y;
            sBs[k0B + 6][nB] = bv1.z; sBs[k0B + 7][nB] = bv1.w;
            __syncthreads();
#pragma unroll
            for (int k4 = 0; k4 < 8; k4++) {
                f4v a4[4];
#pragma unroll
                for (int i = 0; i < 4; i++) a4[i] = *(const f4v*)&sAs[tm + i][k4 * 4];
#pragma unroll
                for (int kk = 0; kk < 4; kk++) {
                    f4v b4 = *(const f4v*)&sBs[k4 * 4 + kk][tn];
#pragma unroll
                    for (int i = 0; i < 4; i++) {
                        acc[i][0] = fmaf(a4[i][kk], b4.x, acc[i][0]);
                        acc[i][1] = fmaf(a4[i][kk], b4.y, acc[i][1]);
                        acc[i][2] = fmaf(a4[i][kk], b4.z, acc[i][2]);
                        acc[i][3] = fmaf(a4[i][kk], b4.w, acc[i][3]);
                    }
                }
            }
        }
        // epilogue: ph + score partials (vectorized plain px read; LDS factors)
        float spart[4];
#pragma unroll
        for (int i = 0; i < 4; i++) {
            int t = m0 + tm + i;
            size_t prow = ((size_t)b * 256 + t) * 128;
            f4v pxv = *(const f4v*)(px + prow + tn);
            float sp = 0.f;
#pragma unroll
            for (int j = 0; j < 4; j++) {
                int col = tn + j;
                float val = acc[i][j] + proj_h_b[col];
                ast_(phg + prow + col, val);
                float inx = (pxv[j] - smu[col]) * siv[col];
                sp = fmaf(tanh_(val + inx), attn_w[col], sp);
            }
            spart[i] = sp;
        }
        __syncthreads();
#pragma unroll
        for (int i = 0; i < 4; i++) sred[tm + i][tid & 31] = spart[i];
        __syncthreads();
        if (tid < 64) {
            float s = 0.f;
#pragma unroll
            for (int j = 0; j < 32; j++) s += sred[tid][j];
            ast_(lsc + b * 256 + m0 + tid, s);
        }
        __syncthreads();   // drains vmcnt: ph + lsc visible
        if (tid == 0) {
            (void)__hip_atomic_fetch_add(cnt + b, 1, __ATOMIC_ACQ_REL, __HIP_MEMORY_SCOPE_AGENT);
            wait_ge_(cnt + b, 4);
        }
        __syncthreads();
        // softmax over lsc[b][0..255] (redundant per block, cheap; plain loads OK)
        float v = 0.f;
        if (tid < 256) { v = lsc[b * 256 + tid]; stmp[tid] = v; }
        __syncthreads();
        for (int off = 128; off > 0; off >>= 1) {
            if (tid < off) stmp[tid] = fmaxf(stmp[tid], stmp[tid + off]);
            __syncthreads();
        }
        float mx = stmp[0];
        __syncthreads();
        float e = (tid < 256) ? __expf(v - mx) : 0.f;
        if (tid < 256) stmp[tid] = e;
        __syncthreads();
        for (int off = 128; off > 0; off >>= 1) {
            if (tid < off) stmp[tid] += stmp[tid + off];
            __syncthreads();
        }
        float tot = stmp[0];
        __syncthreads();
        if (tid < 256) swsh[tid] = e / tot;
        __syncthreads();
        {   // attention-map quarter (alpha = softmax_t / D, constant across d)
            float* ob = out_att + (size_t)b * T_ * D_ + (size_t)m0 * 128;
            const float invD = 1.f / (float)D_;
            for (int i = tid; i < 64 * 128; i += 512)
                ob[i] = swsh[m0 + (i >> 7)] * invD;
        }
        if (qt == 0) {   // context + FC
            int h = tid & 127, st = tid >> 7;
            float a = 0.f;
            for (int tt = st * 64; tt < st * 64 + 64; tt++)
                a = fmaf(phg[((size_t)b * 256 + tt) * 128 + h], swsh[tt], a);
            sctx[st * 128 + h] = a;
            __syncthreads();
            if (tid < 128) sctx[tid] = sctx[tid] + sctx[128 + tid] + sctx[256 + tid] + sctx[384 + tid];
            __syncthreads();
            if (tid < NC_) {
                float s = fc_b[tid];
                const float* fw = fc_w + tid * 128;
                for (int k = 0; k < 128; k++) s = fmaf(sctx[k], fw[k], s);
                out[b * NC_ + tid] = s;
            }
        }
    } else {
        // ======== input-stats rider: b = wg - 224 ========
        const int b = wg - 224;
        const int d = tid & 127, r = tid >> 7;
        const float* xb = x + (size_t)b * T_ * 128;
        float s = 0.f, q = 0.f;
        for (int t = r; t < T_; t += 4) {
            float v = xb[(size_t)t * 128 + d];
            s += v; q += v * v;
        }
        shbuf[tid] = s; shbuf[512 + tid] = q;
        __syncthreads();
        if (r == 0) {
            s = shbuf[d] + shbuf[128 + d] + shbuf[256 + d] + shbuf[384 + d];
            q = shbuf[512 + d] + shbuf[640 + d] + shbuf[768 + d] + shbuf[896 + d];
            ast_(psumB + b * 128 + d, s);
            ast_(psqB + b * 128 + d, q);
        }
        __syncthreads();   // drains vmcnt: partials visible
        if (tid == 0) {
            (void)__hip_atomic_fetch_add(cnt_s, 1, __ATOMIC_ACQ_REL, __HIP_MEMORY_SCOPE_AGENT);
            wait_ge_(cnt_s, 16);
        }
        __syncthreads();   // acquire L1-inv applied CU-wide
        if (tid < 128) {
            float S = 0.f, Q = 0.f, sb = 0.f, qb = 0.f;
            for (int bb = 0; bb < 16; bb++) {
                float ps = psumB[bb * 128 + tid];   // plain after acquire
                float pq = psqB[bb * 128 + tid];
                S += ps; Q += pq;
                if (bb == b) { sb = ps; qb = pq; }
            }
            float n = (float)(B_ * T_);
            float m = S / n;
            float varu = (Q - n * m * m) / (n - 1.f);
            float sd = sqrtf(fmaxf(varu, 0.f)) + EPS_;
            float mu = sb * (1.f / T_);
            float varT = qb * (1.f / T_) - mu * mu;
            ast_(mu_bd + b * 128 + tid, mu);
            ast_(invn + b * 128 + tid, rsqrtf(fmaxf(varT, 0.f) + EPS_ * sd * sd));
        }
        __syncthreads();   // drains vmcnt: factors visible
        if (tid == 0) __hip_atomic_store(flag_norm + b, 1, __ATOMIC_RELEASE, __HIP_MEMORY_SCOPE_AGENT);
    }
}

// ---------------- launcher ----------------
extern "C" void kernel_launch(void* const* d_in, const int* in_sizes, int n_in,
                              void* d_out, int out_size, void* d_ws, size_t ws_size,
                              hipStream_t stream) {
    const float* x        = (const float*)d_in[0];
    const float* Wih      = (const float*)d_in[1];
    const float* Whh      = (const float*)d_in[2];
    const float* bih      = (const float*)d_in[3];
    const float* bhh      = (const float*)d_in[4];
    const float* proj_h_w = (const float*)d_in[5];
    const float* proj_h_b = (const float*)d_in[6];
    const float* proj_x_w = (const float*)d_in[7];
    const float* proj_x_b = (const float*)d_in[8];
    const float* attn_w   = (const float*)d_in[9];
    const float* fc_w     = (const float*)d_in[10];
    const float* fc_b     = (const float*)d_in[11];
    float* out = (float*)d_out;

    float* ws = (float*)d_ws;
    const size_t NTD = (size_t)B_ * T_ * D_;       // 524288
    float* h_glob = ws;                            // 4*NTD
    float* ring   = h_glob + 4 * NTD;              // 4*NTD
    float* px     = ring + 4 * NTD;                // 1*NTD
    float* smalls = px + NTD;
    float* psumB  = smalls;                        // 16*128
    float* psqB   = psumB + 2048;                  // 16*128
    float* mu_bd  = psqB + 2048;
    float* invn   = mu_bd + 2048;
    float* mu_ln  = invn + 2048;
    float* inv_ln = mu_ln + 2048;
    float* mu_px  = inv_ln + 2048;
    float* inv_px = mu_px + 2048;
    float* lsc    = inv_px + 2048;
    int*   flags  = (int*)(lsc + 4096);
    int*   flag_h   = flags;                       // [64]
    int*   flag_g   = flags + 64;                  // [64]
    int*   flag_px  = flags + 128;                 // [16]
    int*   flag_ln  = flags + 144;                 // [16]
    int*   cnt      = flags + 160;                 // [16]
    int*   flag_norm= flags + 176;                 // [16]
    int*   cnt_s    = flags + 192;                 // [1]

    hipMemsetAsync((void*)flags, 0, 256 * sizeof(int), stream);

    // single fused dispatch: stats + 4-layer LSTM pipeline + all riders + tail
    megascan<<<240, 512, 0, stream>>>(x, Wih, Whh, bih, bhh,
                                      proj_x_w, proj_x_b, proj_h_w, proj_h_b,
                                      attn_w, fc_w, fc_b,
                                      mu_bd, invn, psumB, psqB,
                                      h_glob, ring, px,
                                      mu_px, inv_px, mu_ln, inv_ln,
                                      lsc, out, out + B_ * NC_,
                                      flag_h, flag_g, flag_px, flag_ln, cnt,
                                      flag_norm, cnt_s);
}